// Round 14
// baseline (426.799 us; speedup 1.0000x reference)
//
#include <hip/hip_runtime.h>
#include <cstdint>

typedef short short8 __attribute__((ext_vector_type(8)));
typedef float f32x4 __attribute__((ext_vector_type(4)));

#define LDS_AS3(p) ((__attribute__((address_space(3))) unsigned*)(p))
#define GLB_AS1(p) ((const __attribute__((address_space(1))) unsigned*)(p))

// fp32 -> bf16 (round-to-nearest-even), two packed into a u32
__device__ inline unsigned bfpack(float a, float b) {
    union { float f; unsigned u; } ua, ub;
    ua.f = a; ub.f = b;
    unsigned lo = (ua.u + 0x7FFFu + ((ua.u >> 16) & 1u)) >> 16;
    unsigned hi = (ub.u + 0x7FFFu + ((ub.u >> 16) & 1u)) & 0xFFFF0000u;
    return lo | hi;
}
__device__ inline unsigned short bf16of(float a) { return (unsigned short)bfpack(a, 0.0f); }
__device__ inline float ubits(unsigned u) { union { unsigned x; float f; } c; c.x = u; return c.f; }

// ---------------- prepass: convert X to bf16 (same [.,448,512] layout) ------
__global__ __launch_bounds__(256)
void cvt_x(const float* __restrict__ X, unsigned short* __restrict__ XB)
{
    const int g = blockIdx.x * 256 + threadIdx.x;
    const float4 v0 = *(const float4*)(X + (size_t)g * 8);
    const float4 v1 = *(const float4*)(X + (size_t)g * 8 + 4);
    uint4 u;
    u.x = bfpack(v0.x, v0.y); u.y = bfpack(v0.z, v0.w);
    u.z = bfpack(v1.x, v1.y); u.w = bfpack(v1.z, v1.w);
    *(uint4*)(XB + (size_t)g * 8) = u;
}

// ------------- prepass: convert + transpose W[512][N] -> WT[N][512] bf16 ----
template <int N>
__global__ __launch_bounds__(256)
void cvt_w(const float* __restrict__ W, unsigned short* __restrict__ WT)
{
    const int g = blockIdx.x * 256 + threadIdx.x;
    if (g >= N * 64) return;
    const int n = g % N, d8 = g / N;
    const float* p = W + (size_t)d8 * 8 * N + n;
    uint4 u;
    u.x = bfpack(p[0],             p[(size_t)N]);
    u.y = bfpack(p[2 * (size_t)N], p[3 * (size_t)N]);
    u.z = bfpack(p[4 * (size_t)N], p[5 * (size_t)N]);
    u.w = bfpack(p[6 * (size_t)N], p[7 * (size_t)N]);
    *(uint4*)(WT + (size_t)n * 512 + d8 * 8) = u;
}

// --------- 256x256 GEMM (R10 K-loop) + transposed-EXT coalesced epilogue ----
// EXT buffers are stored TRANSPOSED (EXT0T[b][kn][kd0*9+j], EXT1T[b][kn2]
// [kd1*9+j]): the producing block holds all kd for each b in its LDS tile, so
// T-rows are written dense (col = i*64+lane -> 128B/instr); consumers read
// fully contiguous runs (uint2 at nb). MODE2's panel + 4-pass structure gone.
template <int MODE>
__global__ __launch_bounds__(1024, 4)
void gemm_big(const unsigned short* __restrict__ XB,
              const unsigned short* __restrict__ WT,
              const float* __restrict__ BIAS, float* __restrict__ Y,
              const unsigned short* __restrict__ EXTI,
              unsigned short* __restrict__ EXTO)
{
    constexpr int K_L  = (MODE == 0) ? 64 : (MODE == 1) ? 128 : 256;
    constexpr int LOGK = (MODE == 0) ? 6  : (MODE == 1) ? 7   : 8;
    constexpr int N    = (MODE == 0) ? 1180 : (MODE == 1) ? 2881 : 1153;
    constexpr int XOFF = (MODE == 0) ? 0 : (MODE == 1) ? 64 : 192;
    constexpr int NT   = (N + 255) / 256;

    __shared__ __align__(16) char smem[133120];          // K-loop 128KB / epi 130KB
    unsigned short* lAp = (unsigned short*)smem;
    unsigned short* lBp = lAp + 2 * 256 * 64;

    const int t    = threadIdx.x;
    const int lane = t & 63;
    const int wv   = t >> 6;
    const int wr   = wv >> 2;
    const int wc   = wv & 3;
    const int kq   = lane >> 4;
    const int lr16 = lane & 15;

    const int cpx = (int)gridDim.x >> 3;
    const int wg  = (blockIdx.x & 7) * cpx + (blockIdx.x >> 3);
    const int nt  = wg % NT;
    const int mt  = wg / NT;
    const int m0  = mt * 256;
    const int n0  = nt * 256;

    auto stage = [&](int buf, int kt) {
        #pragma unroll
        for (int i = 0; i < 2; ++i) {
            const int c   = i * 1024 + t;
            const int row = c >> 3, p = c & 7, l = p ^ (row & 7);
            const int m   = m0 + row;
            const int b   = m >> LOGK, kd = m & (K_L - 1);
            const unsigned short* gp =
                XB + ((size_t)(b * 448 + XOFF + kd) << 9) + kt * 64 + l * 8;
            __builtin_amdgcn_global_load_lds(GLB_AS1(gp),
                LDS_AS3(lAp + buf * 16384 + c * 8), 16, 0, 0);
        }
        #pragma unroll
        for (int i = 0; i < 2; ++i) {
            const int c   = i * 1024 + t;
            const int row = c >> 3, p = c & 7, l = p ^ (row & 7);
            int gc = n0 + row; if (gc > N - 1) gc = N - 1;
            const unsigned short* gp = WT + (size_t)gc * 512 + kt * 64 + l * 8;
            __builtin_amdgcn_global_load_lds(GLB_AS1(gp),
                LDS_AS3(lBp + buf * 16384 + c * 8), 16, 0, 0);
        }
    };

    f32x4 acc[4][4] = {};

    // ---- K loop (R10 verbatim) -------------------------------------------
    stage(0, 0);
    __syncthreads();
    #pragma unroll 1
    for (int kt = 0; kt < 8; ++kt) {
        const int buf = kt & 1;
        if (kt < 7) stage(buf ^ 1, kt + 1);
        #pragma unroll
        for (int ks = 0; ks < 2; ++ks) {
            const int s = ks * 4 + kq;
            short8 af[4], bf[4];
            #pragma unroll
            for (int mi = 0; mi < 4; ++mi) {
                const int row = wr * 64 + mi * 16 + lr16;
                af[mi] = *(const short8*)(lAp + buf * 16384 + row * 64 + ((s ^ (row & 7)) * 8));
            }
            #pragma unroll
            for (int ni = 0; ni < 4; ++ni) {
                const int row = wc * 64 + ni * 16 + lr16;
                bf[ni] = *(const short8*)(lBp + buf * 16384 + row * 64 + ((s ^ (row & 7)) * 8));
            }
            __builtin_amdgcn_s_setprio(1);
            #pragma unroll
            for (int mi = 0; mi < 4; ++mi)
                #pragma unroll
                for (int ni = 0; ni < 4; ++ni)
                    acc[mi][ni] = __builtin_amdgcn_mfma_f32_16x16x32_bf16(
                        af[mi], bf[ni], acc[mi][ni], 0, 0, 0);
            __builtin_amdgcn_s_setprio(0);
        }
        __syncthreads();
    }

    // ================= epilogue: 2 passes of 128 rows =================
    float* LDSf = (float*)smem;                       // [128][260]

    #pragma unroll 1
    for (int h = 0; h < 2; ++h) {
        if (h) __syncthreads();
        if ((wr >> 1) == h) {
            const int mb = (wr & 1) * 64;
            #pragma unroll
            for (int mi = 0; mi < 4; ++mi)
                #pragma unroll
                for (int ni = 0; ni < 4; ++ni)
                    #pragma unroll
                    for (int r = 0; r < 4; ++r)
                        LDSf[(mb + mi * 16 + kq * 4 + r) * 260 + wc * 64 + ni * 16 + lr16]
                            = acc[mi][ni][r];
        }
        __syncthreads();

        if constexpr (MODE == 0) {
            // ---- EXT0T writes: rows (b, kn), cols kd0*9+j (576) ----------
            const int lo = (n0 > 28) ? n0 : 28;
            const int hi = (n0 + 256 < 1180) ? n0 + 256 : 1180;
            const int kn_lo = (lo - 28) / 9, kn_hi = (hi - 29) / 9;
            const int b_base = (m0 + h * 128) >> 6;
            #pragma unroll 1
            for (int idx = wv; idx < 2 * (kn_hi - kn_lo + 1); idx += 16) {
                const int bloc = idx & 1, kn = kn_lo + (idx >> 1);
                unsigned short* dst = EXTO + ((size_t)((b_base + bloc) * 128 + kn)) * 576;
                #pragma unroll
                for (int i = 0; i < 9; ++i) {
                    const int col = i * 64 + lane;
                    const int kd0 = col / 9, j = col - kd0 * 9;
                    const int n = 28 + kn * 9 + j;
                    if (n >= lo && n < hi)
                        dst[col] = bf16of(LDSf[(bloc * 64 + kd0) * 260 + (n - n0)] + BIAS[n]);
                }
            }
            // ---- own region (nt==0): cols 0..26 + bias col 27 ------------
            if (n0 == 0) {
                #pragma unroll 1
                for (int rr = 0; rr < 8; ++rr) {
                    const int ml = wv * 8 + rr;
                    const int m  = m0 + h * 128 + ml;
                    const int b  = m >> 6, kd = m & 63;
                    float* yb = Y + (size_t)b * 370816;
                    if (lane < 27)       yb[kd * 27 + lane] = LDSf[ml * 260 + lane] + BIAS[lane];
                    else if (lane == 27) yb[1728 + kd]      = LDSf[ml * 260 + 27] + BIAS[27];
                }
            }
        } else if constexpr (MODE == 1) {
            // ---- EXT1T writes: rows (b, kn2), cols kd1*9+j (1152) --------
            const int lo = (n0 > 577) ? n0 : 577;
            const int hi = (n0 + 256 < 2881) ? n0 + 256 : 2881;
            const int b  = (m0 >> 7) + h;
            if (lo < hi) {
                const int k_lo = (lo - 577) / 9, k_hi = (hi - 578) / 9;
                #pragma unroll 1
                for (int idx = wv; idx <= k_hi - k_lo; idx += 16) {
                    const int kn2 = k_lo + idx;
                    unsigned short* dst = EXTO + ((size_t)(b * 256 + kn2)) * 1152;
                    #pragma unroll
                    for (int i = 0; i < 18; ++i) {
                        const int col = i * 64 + lane;
                        const int kd1 = col / 9, j = col - kd1 * 9;
                        const int n = 577 + kn2 * 9 + j;
                        if (n >= lo && n < hi)
                            dst[col] = bf16of(LDSf[kd1 * 260 + (n - n0)] + BIAS[n]);
                    }
                }
            }
            // ---- own region ----------------------------------------------
            if (n0 + 255 < 576) {                     // nt 0,1: pure vector
                #pragma unroll 1
                for (int rr = 0; rr < 8; ++rr) {
                    const int ml = wv * 8 + rr;
                    const int m  = m0 + h * 128 + ml;
                    const int bb = m >> 7, kd = m & 127;
                    const int nb = n0 + lane * 4;
                    const float4 v4 = *(const float4*)&LDSf[ml * 260 + lane * 4];
                    const float4 b4 = *(const float4*)(BIAS + nb);
                    const uint2 e2 = *(const uint2*)(EXTI + ((size_t)(bb * 128 + kd)) * 576 + nb);
                    float4 o;
                    o.x = 0.5f * (v4.x + b4.x + ubits(e2.x << 16));
                    o.y = 0.5f * (v4.y + b4.y + ubits(e2.x & 0xFFFF0000u));
                    o.z = 0.5f * (v4.z + b4.z + ubits(e2.y << 16));
                    o.w = 0.5f * (v4.w + b4.w + ubits(e2.y & 0xFFFF0000u));
                    *(float4*)(Y + (size_t)bb * 370816 + 1792 + kd * 576 + nb) = o;
                }
            } else if (n0 <= 576) {                   // nt==2: scalar sliver
                #pragma unroll 1
                for (int rr = 0; rr < 8; ++rr) {
                    const int ml = wv * 8 + rr;
                    const int m  = m0 + h * 128 + ml;
                    const int bb = m >> 7, kd = m & 127;
                    const int n  = n0 + lane;         // 512..575
                    if (n < 576) {
                        const float e = ubits((unsigned)EXTI[((size_t)(bb * 128 + kd)) * 576 + n] << 16);
                        Y[(size_t)bb * 370816 + 1792 + kd * 576 + n] =
                            0.5f * (LDSf[ml * 260 + lane] + BIAS[n] + e);
                    }
                    if (lane == 0)
                        Y[(size_t)bb * 370816 + 75520 + kd] =
                            0.5f * (LDSf[ml * 260 + 64] + BIAS[576]);
                }
            }
        } else {
            // ---- MODE2: pure coalesced own writes (EXT1T reads contiguous)
            const int hi_own = (n0 + 256 < 1152) ? n0 + 256 : 1152;
            #pragma unroll 1
            for (int rr = 0; rr < 8; ++rr) {
                const int ml = wv * 8 + rr;
                const int m  = m0 + h * 128 + ml;
                const int bb = m >> 8, kd = m & 255;
                const int nb = n0 + lane * 4;
                float* yb = Y + (size_t)bb * 370816;
                if (nb + 3 < hi_own) {
                    const float4 v4 = *(const float4*)&LDSf[ml * 260 + lane * 4];
                    const float4 b4 = *(const float4*)(BIAS + nb);
                    const uint2 e2 = *(const uint2*)(EXTI + ((size_t)(bb * 256 + kd)) * 1152 + nb);
                    float4 o;
                    o.x = v4.x + b4.x + ubits(e2.x << 16);
                    o.y = v4.y + b4.y + ubits(e2.x & 0xFFFF0000u);
                    o.z = v4.z + b4.z + ubits(e2.y << 16);
                    o.w = v4.w + b4.w + ubits(e2.y & 0xFFFF0000u);
                    *(float4*)(yb + 75648 + kd * 1152 + nb) = o;
                }
                if (n0 + 256 > 1152 && lane == 32)    // bias col n=1152 (nt==4)
                    yb[370560 + kd] = LDSf[ml * 260 + 128] + BIAS[1152];
            }
        }
    }
}

extern "C" void kernel_launch(void* const* d_in, const int* in_sizes, int n_in,
                              void* d_out, int out_size, void* d_ws, size_t ws_size,
                              hipStream_t stream)
{
    const float* x  = (const float*)d_in[0];
    const float* W0 = (const float*)d_in[1];
    const float* b0 = (const float*)d_in[2];
    const float* W1 = (const float*)d_in[3];
    const float* b1 = (const float*)d_in[4];
    const float* W2 = (const float*)d_in[5];
    const float* b2 = (const float*)d_in[6];
    float* y = (float*)d_out;

    // ws (bf16): XB | WT0 | WT1 | WT2 | EXT0T[128*128*576] | EXT1T[128*256*1152]
    unsigned short* XB    = (unsigned short*)d_ws;
    unsigned short* WT0   = XB    + (size_t)128 * 448 * 512;
    unsigned short* WT1   = WT0   + (size_t)1180 * 512;
    unsigned short* WT2   = WT1   + (size_t)2881 * 512;
    unsigned short* EXT0T = WT2   + (size_t)1153 * 512;
    unsigned short* EXT1T = EXT0T + (size_t)128 * 128 * 576;

    cvt_x<<<dim3(14336), 256, 0, stream>>>(x, XB);
    cvt_w<1180><<<dim3((1180 * 64 + 255) / 256), 256, 0, stream>>>(W0, WT0);
    cvt_w<2881><<<dim3((2881 * 64 + 255) / 256), 256, 0, stream>>>(W1, WT1);
    cvt_w<1153><<<dim3((1153 * 64 + 255) / 256), 256, 0, stream>>>(W2, WT2);

    // grids: (M/256) * ceil(N/256); stream order = EXT dependency
    gemm_big<0><<<dim3(32 * 5),  1024, 0, stream>>>(XB, WT0, b0, y, nullptr, EXT0T);
    gemm_big<1><<<dim3(64 * 12), 1024, 0, stream>>>(XB, WT1, b1, y, EXT0T, EXT1T);
    gemm_big<2><<<dim3(128 * 5), 1024, 0, stream>>>(XB, WT2, b2, y, EXT1T, nullptr);
}